// Round 10
// baseline (114.817 us; speedup 1.0000x reference)
//
#include <hip/hip_runtime.h>
#include <math.h>

#define N_NODES 50000
#define N_EDGES 800000
#define IN_DIM 256
#define HID 64
#define BKT 256
#define NBKT ((N_NODES + BKT - 1) / BKT)          // 196
#define CAP 8192                                  // ebuf slots per bucket (max real ~4400)
#define CHUNK 4096
#define NCH ((N_EDGES + CHUNK - 1) / CHUNK)       // 196
#define NGB ((N_NODES + 63) / 64)                 // 782

typedef short short8v __attribute__((ext_vector_type(8)));
typedef float f32x4 __attribute__((ext_vector_type(4)));
typedef unsigned uint4v __attribute__((ext_vector_type(4)));

__device__ __forceinline__ unsigned short f2bf(float f) {
  unsigned u = __builtin_bit_cast(unsigned, f);
  u += 0x7FFFu + ((u >> 16) & 1u);  // RNE
  return (unsigned short)(u >> 16);
}
__device__ __forceinline__ unsigned pack2(float a, float b) {
  return (unsigned)f2bf(a) | ((unsigned)f2bf(b) << 16);
}
__device__ __forceinline__ float bfu_lo(unsigned u) {
  return __builtin_bit_cast(float, u << 16);
}
__device__ __forceinline__ float bfu_hi(unsigned u) {
  return __builtin_bit_cast(float, u & 0xFFFF0000u);
}

// ---------------- prep: zero counters + convert/transpose weights ----------------
// zb layout: bcur[256] @0, dhist[64] @256, doff[64] @320  (384 ints total)
__global__ void k_prep(int* __restrict__ zb, const float* __restrict__ W1,
                       const float* __restrict__ W2, unsigned short* __restrict__ Wt1,
                       unsigned short* __restrict__ Wt2) {
  const int t = threadIdx.x;
  if (blockIdx.x == 0) {
    for (int i = t; i < 384; i += 256) zb[i] = 0;
  } else if (blockIdx.x == 1) {
    for (int j = 0; j < 64; ++j) {
      int lin = j * 256 + t;
      int k = lin >> 6, c = lin & 63;
      Wt1[c * 256 + k] = f2bf(W1[lin]);
    }
  } else {
    for (int j = 0; j < 16; ++j) {
      int lin = j * 256 + t;
      int k = lin >> 6, c = lin & 63;
      Wt2[c * 64 + k] = f2bf(W2[lin]);
    }
  }
}

// ---------------- split: LDS-staged bucket sort, dense write-out ----------------
// entry = (bucket<<24) | (src<<8) | dstLocal
__global__ __launch_bounds__(256) void k_split(const int* __restrict__ src,
                                               const int* __restrict__ dst,
                                               int* __restrict__ bcur,
                                               unsigned* __restrict__ ebuf) {
  __shared__ unsigned stage[CHUNK];  // 16KB
  __shared__ int cnt[256];
  __shared__ int off[256];
  __shared__ int gbase[256];
  __shared__ int lcur[256];
  const int t = threadIdx.x;
  const int base = blockIdx.x * CHUNK;
  const int valid = min(CHUNK, N_EDGES - base);

  cnt[t] = 0;
  __syncthreads();
#pragma unroll
  for (int i = 0; i < CHUNK / 256; ++i) {
    int e = base + i * 256 + t;
    if (e < N_EDGES) atomicAdd(&cnt[dst[e] >> 8], 1);
  }
  __syncthreads();
  {
    int c = cnt[t];
    off[t] = c;
    __syncthreads();
    for (int d = 1; d < 256; d <<= 1) {
      int v = off[t];
      int a = (t >= d) ? off[t - d] : 0;
      __syncthreads();
      off[t] = v + a;
      __syncthreads();
    }
    int ex = off[t] - c;
    off[t] = ex;
    lcur[t] = ex;
    gbase[t] = (t < NBKT && c) ? (t * CAP + atomicAdd(&bcur[t], c)) : 0;
  }
  __syncthreads();
#pragma unroll
  for (int i = 0; i < CHUNK / 256; ++i) {
    int e = base + i * 256 + t;
    if (e < N_EDGES) {
      int d = dst[e];
      int b = d >> 8;
      int p = atomicAdd(&lcur[b], 1);
      stage[p] = ((unsigned)b << 24) | ((unsigned)src[e] << 8) | (unsigned)(d & 255);
    }
  }
  __syncthreads();
  for (int i = t; i < valid; i += 256) {
    unsigned u = stage[i];
    int b = u >> 24;
    ebuf[gbase[b] + (i - off[b])] = u;
  }
}

// ---------------- bucket: per-bucket fine CSR + degree histogram ----------------
__global__ void k_bucket(const unsigned* __restrict__ ebuf, const int* __restrict__ bcur,
                         int* __restrict__ rowptr, int* __restrict__ colidx,
                         float* __restrict__ dinv, int* __restrict__ dhist) {
  __shared__ int sA[256];
  __shared__ int sB[256];
  __shared__ int dh[64];
  const int b = blockIdx.x, t = threadIdx.x;

  sA[t] = (t < NBKT) ? bcur[t] : 0;
  __syncthreads();
  for (int d = 1; d < 256; d <<= 1) {
    int v = sA[t];
    int a = (t >= d) ? sA[t - d] : 0;
    __syncthreads();
    sA[t] = v + a;
    __syncthreads();
  }
  const int prefix = (b == 0) ? 0 : sA[b - 1];
  const int cntb = bcur[b];
  const int sbeg = b * CAP, send = sbeg + cntb;
  __syncthreads();

  sA[t] = 0;
  __syncthreads();
  for (int i = sbeg + t; i < send; i += 256) atomicAdd(&sA[ebuf[i] & 255], 1);
  __syncthreads();
  const int myc = sA[t];
  sB[t] = myc;
  __syncthreads();
  for (int d = 1; d < 256; d <<= 1) {
    int v = sB[t];
    int a = (t >= d) ? sB[t - d] : 0;
    __syncthreads();
    sB[t] = v + a;
    __syncthreads();
  }
  const int node = b * BKT + t;
  const int ex = prefix + sB[t] - myc;
  if (node < N_NODES) {
    rowptr[node] = ex;
    dinv[node] = rsqrtf((float)(myc + 1));
    if (node == N_NODES - 1) rowptr[N_NODES] = N_EDGES;
  }
  __syncthreads();
  sB[t] = ex;
  __syncthreads();
  for (int i = sbeg + t; i < send; i += 256) {
    unsigned p = ebuf[i];
    int pos = atomicAdd(&sB[p & 255], 1);
    colidx[pos] = (int)((p >> 8) & 0xFFFFu);
  }
  // degree histogram (bins 0..63, clamp)
  if (t < 64) dh[t] = 0;
  __syncthreads();
  if (node < N_NODES) atomicAdd(&dh[myc < 63 ? myc : 63], 1);
  __syncthreads();
  if (t < 64 && dh[t]) atomicAdd(&dhist[t], dh[t]);
}

// ---------------- perm: degree-sorted node permutation ----------------
__global__ __launch_bounds__(256) void k_perm(const int* __restrict__ rowptr,
                                              const int* __restrict__ dhist,
                                              int* __restrict__ doff,
                                              int* __restrict__ perm) {
  __shared__ int dbase[64];
  __shared__ int lh[64];
  __shared__ int lbase[64];
  const int t = threadIdx.x;
  if (t < 64) { dbase[t] = dhist[t]; lh[t] = 0; }
  __syncthreads();
  for (int d = 1; d < 64; d <<= 1) {
    int vv = 0, aa = 0;
    if (t < 64) { vv = dbase[t]; if (t >= d) aa = dbase[t - d]; }
    __syncthreads();
    if (t < 64) dbase[t] = vv + aa;
    __syncthreads();
  }
  const int v = blockIdx.x * 256 + t;
  int bin = 0, myoff = 0;
  const bool ok = v < N_NODES;
  if (ok) {
    int deg = rowptr[v + 1] - rowptr[v];
    bin = deg < 63 ? deg : 63;
    myoff = atomicAdd(&lh[bin], 1);
  }
  __syncthreads();
  if (t < 64) {
    lbase[t] = lh[t] ? atomicAdd(&doff[t], lh[t]) : 0;
    dbase[t] -= dhist[t];  // inclusive -> exclusive
  }
  __syncthreads();
  if (ok) perm[dbase[bin] + lbase[bin] + myoff] = v;
}

// ---------------- edinv: dinvE[e] = dinv[colidx[e]] ----------------
__global__ __launch_bounds__(256) void k_edinv(const int* __restrict__ colidx,
                                               const float* __restrict__ dinv,
                                               float* __restrict__ dinvE) {
  int i = (blockIdx.x * 256 + threadIdx.x) * 4;
  if (i < N_EDGES) {
    int4 c = *reinterpret_cast<const int4*>(&colidx[i]);
    float4 o;
    o.x = dinv[c.x]; o.y = dinv[c.y]; o.z = dinv[c.z]; o.w = dinv[c.w];
    *reinterpret_cast<float4*>(&dinvE[i]) = o;
  }
}

// ---------------- GEMM1: Wt1 in LDS, deep A-register prefetch ----------------
__global__ __launch_bounds__(256) void k_gemm1(const float* __restrict__ X,
                                               const unsigned short* __restrict__ Wt1g,
                                               unsigned short* __restrict__ outA) {
  __shared__ unsigned short Wl[64][IN_DIM + 8];
  const int t = threadIdx.x, lane = t & 63, wv = t >> 6;

#pragma unroll
  for (int j = 0; j < 8; ++j) {
    int grp = j * 256 + t;
    int r = grp >> 5, c = (grp & 31) * 8;
    *reinterpret_cast<short8v*>(&Wl[r][c]) =
        *reinterpret_cast<const short8v*>(&Wt1g[r * IN_DIM + c]);
  }

  const int row0 = blockIdx.x * 64;
  int r = row0 + wv * 16 + (lane & 15);
  if (r > N_NODES - 1) r = N_NODES - 1;
  const int kh = (lane >> 4) * 8;

  uint4v ap[8];
#pragma unroll
  for (int k0 = 0; k0 < 8; ++k0) {
    const float* Xp = X + (size_t)r * IN_DIM + k0 * 32 + kh;
    const float4 x0 = *reinterpret_cast<const float4*>(Xp);
    const float4 x1 = *reinterpret_cast<const float4*>(Xp + 4);
    uint4v p;
    p.x = pack2(x0.x, x0.y); p.y = pack2(x0.z, x0.w);
    p.z = pack2(x1.x, x1.y); p.w = pack2(x1.z, x1.w);
    ap[k0] = p;
  }
  __syncthreads();

  f32x4 acc[4] = {};
#pragma unroll
  for (int k0 = 0; k0 < 8; ++k0) {
    short8v a = __builtin_bit_cast(short8v, ap[k0]);
#pragma unroll
    for (int n = 0; n < 4; ++n) {
      short8v b = *reinterpret_cast<const short8v*>(&Wl[n * 16 + (lane & 15)][k0 * 32 + kh]);
      acc[n] = __builtin_amdgcn_mfma_f32_16x16x32_bf16(a, b, acc[n], 0, 0, 0);
    }
  }

  const int r0 = row0 + wv * 16;
#pragma unroll
  for (int j = 0; j < 4; ++j) {
    int rr = r0 + (lane >> 4) * 4 + j;
    if (rr < N_NODES) {
#pragma unroll
      for (int n = 0; n < 4; ++n)
        outA[(size_t)rr * 64 + n * 16 + (lane & 15)] = f2bf(acc[n][j]);
    }
  }
}

// ---------------- agg1 (perm'd, fma-scaled gather) + bias/relu + GEMM2 fused ----------------
__global__ __launch_bounds__(256) void k_agg_gemm(
    const unsigned short* __restrict__ h, const int* __restrict__ rowptr,
    const int* __restrict__ col, const float* __restrict__ dinv,
    const float* __restrict__ dinvE, const float* __restrict__ bias,
    const unsigned short* __restrict__ Wt2g, const int* __restrict__ perm,
    unsigned short* __restrict__ out) {
  const int t = threadIdx.x, lane = t & 63, wv = t >> 6;
  const int g = lane >> 3, f0 = (lane & 7) * 8;
  const int vbase = blockIdx.x * 32;
  const int lrow = wv * 8 + g;

  __shared__ unsigned short h1s[32][72];
  __shared__ int pvs[32];
  __shared__ float sdv[32];
  if (t < 32) {
    int p = (vbase + t < N_NODES) ? perm[vbase + t] : -1;
    pvs[t] = p;
    sdv[t] = (p >= 0) ? dinv[p] : 0.0f;
  }
  __syncthreads();

  const int pv = pvs[lrow];
  if (pv >= 0) {
    int e = rowptr[pv];
    const int end = rowptr[pv + 1];
    const float sv = sdv[lrow];

    uint4 sw = *reinterpret_cast<const uint4*>(&h[(size_t)pv * 64 + f0]);
    float acc0 = sv * bfu_lo(sw.x), acc1 = sv * bfu_hi(sw.x);
    float acc2 = sv * bfu_lo(sw.y), acc3 = sv * bfu_hi(sw.y);
    float acc4 = sv * bfu_lo(sw.z), acc5 = sv * bfu_hi(sw.z);
    float acc6 = sv * bfu_lo(sw.w), acc7 = sv * bfu_hi(sw.w);

#define EDGE1(cc, dv)                                                         \
  {                                                                           \
    uint4 w = *reinterpret_cast<const uint4*>(&h[(size_t)(cc) * 64 + f0]);    \
    acc0 = fmaf(dv, bfu_lo(w.x), acc0); acc1 = fmaf(dv, bfu_hi(w.x), acc1);   \
    acc2 = fmaf(dv, bfu_lo(w.y), acc2); acc3 = fmaf(dv, bfu_hi(w.y), acc3);   \
    acc4 = fmaf(dv, bfu_lo(w.z), acc4); acc5 = fmaf(dv, bfu_hi(w.z), acc5);   \
    acc6 = fmaf(dv, bfu_lo(w.w), acc6); acc7 = fmaf(dv, bfu_hi(w.w), acc7);   \
  }
    while (e < end && (e & 3)) { EDGE1(col[e], dinvE[e]); ++e; }
    for (; e + 8 <= end; e += 8) {
      int4 ca = *reinterpret_cast<const int4*>(&col[e]);
      int4 cb = *reinterpret_cast<const int4*>(&col[e + 4]);
      float4 da = *reinterpret_cast<const float4*>(&dinvE[e]);
      float4 db = *reinterpret_cast<const float4*>(&dinvE[e + 4]);
      EDGE1(ca.x, da.x); EDGE1(ca.y, da.y); EDGE1(ca.z, da.z); EDGE1(ca.w, da.w);
      EDGE1(cb.x, db.x); EDGE1(cb.y, db.y); EDGE1(cb.z, db.z); EDGE1(cb.w, db.w);
    }
    for (; e + 4 <= end; e += 4) {
      int4 cc = *reinterpret_cast<const int4*>(&col[e]);
      float4 dd = *reinterpret_cast<const float4*>(&dinvE[e]);
      EDGE1(cc.x, dd.x); EDGE1(cc.y, dd.y); EDGE1(cc.z, dd.z); EDGE1(cc.w, dd.w);
    }
    for (; e < end; ++e) { EDGE1(col[e], dinvE[e]); }
#undef EDGE1

    const float4 ba = *reinterpret_cast<const float4*>(&bias[f0]);
    const float4 bb = *reinterpret_cast<const float4*>(&bias[f0 + 4]);
    float v0 = fmaxf(fmaf(sv, acc0, ba.x), 0.0f);
    float v1 = fmaxf(fmaf(sv, acc1, ba.y), 0.0f);
    float v2 = fmaxf(fmaf(sv, acc2, ba.z), 0.0f);
    float v3 = fmaxf(fmaf(sv, acc3, ba.w), 0.0f);
    float v4 = fmaxf(fmaf(sv, acc4, bb.x), 0.0f);
    float v5 = fmaxf(fmaf(sv, acc5, bb.y), 0.0f);
    float v6 = fmaxf(fmaf(sv, acc6, bb.z), 0.0f);
    float v7 = fmaxf(fmaf(sv, acc7, bb.w), 0.0f);

    uint4 o;
    o.x = pack2(v0, v1); o.y = pack2(v2, v3);
    o.z = pack2(v4, v5); o.w = pack2(v6, v7);
    *reinterpret_cast<uint4*>(&h1s[lrow][f0]) = o;
  } else {
    uint4 z = {0, 0, 0, 0};
    *reinterpret_cast<uint4*>(&h1s[lrow][f0]) = z;
  }
  __syncthreads();

  // GEMM2: 32 tile rows x 64 cols; wave wv owns cols [wv*16, wv*16+16); K=64.
  const int kh = (lane >> 4) * 8;
  f32x4 acc2r[2] = {};
#pragma unroll
  for (int rt = 0; rt < 2; ++rt) {
#pragma unroll
    for (int k0 = 0; k0 < 64; k0 += 32) {
      short8v a = *reinterpret_cast<const short8v*>(&h1s[rt * 16 + (lane & 15)][k0 + kh]);
      short8v b = *reinterpret_cast<const short8v*>(
          Wt2g + (size_t)(wv * 16 + (lane & 15)) * 64 + k0 + kh);
      acc2r[rt] = __builtin_amdgcn_mfma_f32_16x16x32_bf16(a, b, acc2r[rt], 0, 0, 0);
    }
  }
#pragma unroll
  for (int rt = 0; rt < 2; ++rt) {
#pragma unroll
    for (int j = 0; j < 4; ++j) {
      int lr2 = rt * 16 + (lane >> 4) * 4 + j;
      int pvg = pvs[lr2];
      if (pvg >= 0)
        out[(size_t)pvg * 64 + wv * 16 + (lane & 15)] = f2bf(acc2r[rt][j] * sdv[lr2]);
    }
  }
}

// ---------------- agg2 (perm'd, plain adds) + classifier fused ----------------
__global__ __launch_bounds__(256) void k_agg_fin(
    const unsigned short* __restrict__ h, const int* __restrict__ rowptr,
    const int* __restrict__ col, const float* __restrict__ dinv,
    const float* __restrict__ bias, const float* __restrict__ Wc,
    const float* __restrict__ bc, const int* __restrict__ perm,
    float* __restrict__ out) {
  const int t = threadIdx.x, lane = t & 63;
  const int g = lane >> 3, f0 = (lane & 7) * 8;
  const int vidx = blockIdx.x * 32 + (t >> 6) * 8 + g;
  if (vidx >= N_NODES) return;
  const int pv = perm[vidx];

  int e = rowptr[pv];
  const int end = rowptr[pv + 1];

  uint4 sw = *reinterpret_cast<const uint4*>(&h[(size_t)pv * 64 + f0]);
  float acc0 = bfu_lo(sw.x), acc1 = bfu_hi(sw.x);
  float acc2 = bfu_lo(sw.y), acc3 = bfu_hi(sw.y);
  float acc4 = bfu_lo(sw.z), acc5 = bfu_hi(sw.z);
  float acc6 = bfu_lo(sw.w), acc7 = bfu_hi(sw.w);

#define EDGE2(cc)                                                           \
  {                                                                         \
    uint4 w = *reinterpret_cast<const uint4*>(&h[(size_t)(cc) * 64 + f0]);  \
    acc0 += bfu_lo(w.x); acc1 += bfu_hi(w.x);                               \
    acc2 += bfu_lo(w.y); acc3 += bfu_hi(w.y);                               \
    acc4 += bfu_lo(w.z); acc5 += bfu_hi(w.z);                               \
    acc6 += bfu_lo(w.w); acc7 += bfu_hi(w.w);                               \
  }
  while (e < end && (e & 3)) { EDGE2(col[e]); ++e; }
  for (; e + 8 <= end; e += 8) {
    int4 ca = *reinterpret_cast<const int4*>(&col[e]);
    int4 cb = *reinterpret_cast<const int4*>(&col[e + 4]);
    EDGE2(ca.x); EDGE2(ca.y); EDGE2(ca.z); EDGE2(ca.w);
    EDGE2(cb.x); EDGE2(cb.y); EDGE2(cb.z); EDGE2(cb.w);
  }
  for (; e + 4 <= end; e += 4) {
    int4 cc = *reinterpret_cast<const int4*>(&col[e]);
    EDGE2(cc.x); EDGE2(cc.y); EDGE2(cc.z); EDGE2(cc.w);
  }
  for (; e < end; ++e) { EDGE2(col[e]); }
#undef EDGE2

  const float sv = dinv[pv];
  const float4 ba = *reinterpret_cast<const float4*>(&bias[f0]);
  const float4 bb = *reinterpret_cast<const float4*>(&bias[f0 + 4]);
  const float4 wa = *reinterpret_cast<const float4*>(&Wc[f0]);
  const float4 wb = *reinterpret_cast<const float4*>(&Wc[f0 + 4]);
  float p = fmaxf(fmaf(sv, acc0, ba.x), 0.0f) * wa.x +
            fmaxf(fmaf(sv, acc1, ba.y), 0.0f) * wa.y +
            fmaxf(fmaf(sv, acc2, ba.z), 0.0f) * wa.z +
            fmaxf(fmaf(sv, acc3, ba.w), 0.0f) * wa.w +
            fmaxf(fmaf(sv, acc4, bb.x), 0.0f) * wb.x +
            fmaxf(fmaf(sv, acc5, bb.y), 0.0f) * wb.y +
            fmaxf(fmaf(sv, acc6, bb.z), 0.0f) * wb.z +
            fmaxf(fmaf(sv, acc7, bb.w), 0.0f) * wb.w;
  p += __shfl_xor(p, 1);
  p += __shfl_xor(p, 2);
  p += __shfl_xor(p, 4);
  if ((lane & 7) == 0) out[pv] = 1.0f / (1.0f + expf(-(p + bc[0])));
}

extern "C" void kernel_launch(void* const* d_in, const int* in_sizes, int n_in,
                              void* d_out, int out_size, void* d_ws, size_t ws_size,
                              hipStream_t stream) {
  const float* x  = (const float*)d_in[0];
  const int*   ei = (const int*)d_in[1];
  const float* W1 = (const float*)d_in[2];
  const float* b1 = (const float*)d_in[3];
  const float* W2 = (const float*)d_in[4];
  const float* b2 = (const float*)d_in[5];
  const float* Wc = (const float*)d_in[6];
  const float* bc = (const float*)d_in[7];
  float* out = (float*)d_out;

  const int* src = ei;
  const int* dst = ei + N_EDGES;

  // workspace layout (u32 units)
  unsigned* w = (unsigned*)d_ws;
  int*   zb     = (int*)(w + 0);            // 384: bcur[256], dhist[64]@256, doff[64]@320
  int*   bcur   = zb;
  int*   dhist  = zb + 256;
  int*   doff   = zb + 320;
  int*   rowptr = (int*)(w + 384);          // 50432 (needs 50001)
  int*   colidx = (int*)(w + 50816);        // 800000
  unsigned* ebuf = w + 850816;              // 196*8192 = 1605632
  float* dinv   = (float*)(w + 2456448);    // 50176
  float* dinvE  = (float*)(w + 2506624);    // 800000
  int*   perm   = (int*)(w + 3306624);      // 50176
  unsigned short* Wt1g = (unsigned short*)(w + 3356800);  // 16384 ush
  unsigned short* Wt2g = (unsigned short*)(w + 3364992);  // 4096 ush
  unsigned short* A_bf = (unsigned short*)(w + 3367040);  // 3.2M ush
  unsigned short* B_bf = (unsigned short*)(w + 4967040);  // 3.2M ush

  k_prep<<<3, 256, 0, stream>>>(zb, W1, W2, Wt1g, Wt2g);
  k_split<<<NCH, 256, 0, stream>>>(src, dst, bcur, ebuf);
  k_gemm1<<<NGB, 256, 0, stream>>>(x, Wt1g, A_bf);
  k_bucket<<<NBKT, 256, 0, stream>>>(ebuf, bcur, rowptr, colidx, dinv, dhist);
  k_perm<<<NBKT, 256, 0, stream>>>(rowptr, dhist, doff, perm);
  k_edinv<<<(N_EDGES / 4 + 255) / 256, 256, 0, stream>>>(colidx, dinv, dinvE);

  const int NAB = (N_NODES + 31) / 32;  // 1563
  k_agg_gemm<<<NAB, 256, 0, stream>>>(A_bf, rowptr, colidx, dinv, dinvE, b1, Wt2g, perm, B_bf);
  k_agg_fin<<<NAB, 256, 0, stream>>>(B_bf, rowptr, colidx, dinv, b2, Wc, bc, perm, out);
}

// Round 11
// 106.619 us; speedup vs baseline: 1.0769x; 1.0769x over previous
//
#include <hip/hip_runtime.h>
#include <math.h>

#define N_NODES 50000
#define N_EDGES 800000
#define IN_DIM 256
#define HID 64
#define BKT 256
#define NBKT ((N_NODES + BKT - 1) / BKT)          // 196
#define CAP 8192                                  // ebuf slots per bucket (max real ~4400)
#define CHUNK 4096
#define NCH ((N_EDGES + CHUNK - 1) / CHUNK)       // 196
#define NGB ((N_NODES + 63) / 64)                 // 782

typedef short short8v __attribute__((ext_vector_type(8)));
typedef float f32x4 __attribute__((ext_vector_type(4)));
typedef unsigned uint4v __attribute__((ext_vector_type(4)));

__device__ __forceinline__ unsigned short f2bf(float f) {
  unsigned u = __builtin_bit_cast(unsigned, f);
  u += 0x7FFFu + ((u >> 16) & 1u);  // RNE
  return (unsigned short)(u >> 16);
}
__device__ __forceinline__ unsigned pack2(float a, float b) {
  return (unsigned)f2bf(a) | ((unsigned)f2bf(b) << 16);
}
__device__ __forceinline__ float bfu_lo(unsigned u) {
  return __builtin_bit_cast(float, u << 16);
}
__device__ __forceinline__ float bfu_hi(unsigned u) {
  return __builtin_bit_cast(float, u & 0xFFFF0000u);
}

// ---------------- prep: zero bcur + convert/transpose weights ----------------
__global__ void k_prep(int* __restrict__ bcur, const float* __restrict__ W1,
                       const float* __restrict__ W2, unsigned short* __restrict__ Wt1,
                       unsigned short* __restrict__ Wt2) {
  const int t = threadIdx.x;
  if (blockIdx.x == 0) {
    bcur[t] = 0;
  } else if (blockIdx.x == 1) {
    for (int j = 0; j < 64; ++j) {
      int lin = j * 256 + t;
      int k = lin >> 6, c = lin & 63;
      Wt1[c * 256 + k] = f2bf(W1[lin]);
    }
  } else {
    for (int j = 0; j < 16; ++j) {
      int lin = j * 256 + t;
      int k = lin >> 6, c = lin & 63;
      Wt2[c * 64 + k] = f2bf(W2[lin]);
    }
  }
}

// ---------------- split: LDS-staged bucket sort, dense write-out ----------------
// entry = (bucket<<24) | (src<<8) | dstLocal
__global__ __launch_bounds__(256) void k_split(const int* __restrict__ src,
                                               const int* __restrict__ dst,
                                               int* __restrict__ bcur,
                                               unsigned* __restrict__ ebuf) {
  __shared__ unsigned stage[CHUNK];  // 16KB
  __shared__ int cnt[256];
  __shared__ int off[256];
  __shared__ int gbase[256];
  __shared__ int lcur[256];
  const int t = threadIdx.x;
  const int base = blockIdx.x * CHUNK;
  const int valid = min(CHUNK, N_EDGES - base);

  cnt[t] = 0;
  __syncthreads();
#pragma unroll
  for (int i = 0; i < CHUNK / 256; ++i) {
    int e = base + i * 256 + t;
    if (e < N_EDGES) atomicAdd(&cnt[dst[e] >> 8], 1);
  }
  __syncthreads();
  {
    int c = cnt[t];
    off[t] = c;
    __syncthreads();
    for (int d = 1; d < 256; d <<= 1) {
      int v = off[t];
      int a = (t >= d) ? off[t - d] : 0;
      __syncthreads();
      off[t] = v + a;
      __syncthreads();
    }
    int ex = off[t] - c;
    off[t] = ex;
    lcur[t] = ex;
    gbase[t] = (t < NBKT && c) ? (t * CAP + atomicAdd(&bcur[t], c)) : 0;
  }
  __syncthreads();
#pragma unroll
  for (int i = 0; i < CHUNK / 256; ++i) {
    int e = base + i * 256 + t;
    if (e < N_EDGES) {
      int d = dst[e];
      int b = d >> 8;
      int p = atomicAdd(&lcur[b], 1);
      stage[p] = ((unsigned)b << 24) | ((unsigned)src[e] << 8) | (unsigned)(d & 255);
    }
  }
  __syncthreads();
  for (int i = t; i < valid; i += 256) {
    unsigned u = stage[i];
    int b = u >> 24;
    ebuf[gbase[b] + (i - off[b])] = u;
  }
}

// ---------------- bucket: fine CSR + dinv + bucket-local degree-sorted perm ----------------
__global__ void k_bucket(const unsigned* __restrict__ ebuf, const int* __restrict__ bcur,
                         int* __restrict__ rowptr, int* __restrict__ colidx,
                         float* __restrict__ dinv, int* __restrict__ perm) {
  __shared__ int sA[256];
  __shared__ int sB[256];
  __shared__ int dh[64];
  __shared__ int dbase[64];
  const int b = blockIdx.x, t = threadIdx.x;

  // global colidx base via redundant scan of bucket counts
  sA[t] = (t < NBKT) ? bcur[t] : 0;
  __syncthreads();
  for (int d = 1; d < 256; d <<= 1) {
    int v = sA[t];
    int a = (t >= d) ? sA[t - d] : 0;
    __syncthreads();
    sA[t] = v + a;
    __syncthreads();
  }
  const int prefix = (b == 0) ? 0 : sA[b - 1];
  const int cntb = bcur[b];
  const int sbeg = b * CAP, send = sbeg + cntb;
  __syncthreads();

  // per-node degree within bucket
  sA[t] = 0;
  if (t < 64) dh[t] = 0;
  __syncthreads();
  for (int i = sbeg + t; i < send; i += 256) atomicAdd(&sA[ebuf[i] & 255], 1);
  __syncthreads();
  const int myc = sA[t];
  sB[t] = myc;
  __syncthreads();
  for (int d = 1; d < 256; d <<= 1) {
    int v = sB[t];
    int a = (t >= d) ? sB[t - d] : 0;
    __syncthreads();
    sB[t] = v + a;
    __syncthreads();
  }
  const int node = b * BKT + t;
  const bool valid = node < N_NODES;
  const int ex = prefix + sB[t] - myc;
  if (valid) {
    rowptr[node] = ex;
    dinv[node] = rsqrtf((float)(myc + 1));
    if (node == N_NODES - 1) rowptr[N_NODES] = N_EDGES;
  }

  // bucket-local degree sort: counting sort by degree bin (0..63 clamp)
  const int bin = myc < 63 ? myc : 63;
  int rank = 0;
  if (valid) rank = atomicAdd(&dh[bin], 1);
  perm[b * 256 + t] = -1;  // default for unfilled tail slots
  __syncthreads();
  if (t < 64) dbase[t] = dh[t];
  __syncthreads();
  for (int d = 1; d < 64; d <<= 1) {
    int vv = 0, aa = 0;
    if (t < 64) { vv = dbase[t]; if (t >= d) aa = dbase[t - d]; }
    __syncthreads();
    if (t < 64) dbase[t] = vv + aa;
    __syncthreads();
  }
  if (valid) perm[b * 256 + (dbase[bin] - dh[bin]) + rank] = node;

  // fill colidx (cursor in sB)
  __syncthreads();
  sB[t] = ex;
  __syncthreads();
  for (int i = sbeg + t; i < send; i += 256) {
    unsigned p = ebuf[i];
    int pos = atomicAdd(&sB[p & 255], 1);
    colidx[pos] = (int)((p >> 8) & 0xFFFFu);
  }
}

// ---------------- GEMM1: Wt1 in LDS, deep A prefetch, dinv-scaled epilogue ----------------
// outA[r][c] = bf16( dinv[r] * sum_k X[r][k]*W1[k][c] )
__global__ __launch_bounds__(256) void k_gemm1(const float* __restrict__ X,
                                               const unsigned short* __restrict__ Wt1g,
                                               const float* __restrict__ dinv,
                                               unsigned short* __restrict__ outA) {
  __shared__ unsigned short Wl[64][IN_DIM + 8];
  const int t = threadIdx.x, lane = t & 63, wv = t >> 6;

#pragma unroll
  for (int j = 0; j < 8; ++j) {
    int grp = j * 256 + t;
    int r = grp >> 5, c = (grp & 31) * 8;
    *reinterpret_cast<short8v*>(&Wl[r][c]) =
        *reinterpret_cast<const short8v*>(&Wt1g[r * IN_DIM + c]);
  }

  const int row0 = blockIdx.x * 64;
  int r = row0 + wv * 16 + (lane & 15);
  if (r > N_NODES - 1) r = N_NODES - 1;
  const int kh = (lane >> 4) * 8;

  uint4v ap[8];
#pragma unroll
  for (int k0 = 0; k0 < 8; ++k0) {
    const float* Xp = X + (size_t)r * IN_DIM + k0 * 32 + kh;
    const float4 x0 = *reinterpret_cast<const float4*>(Xp);
    const float4 x1 = *reinterpret_cast<const float4*>(Xp + 4);
    uint4v p;
    p.x = pack2(x0.x, x0.y); p.y = pack2(x0.z, x0.w);
    p.z = pack2(x1.x, x1.y); p.w = pack2(x1.z, x1.w);
    ap[k0] = p;
  }
  __syncthreads();

  f32x4 acc[4] = {};
#pragma unroll
  for (int k0 = 0; k0 < 8; ++k0) {
    short8v a = __builtin_bit_cast(short8v, ap[k0]);
#pragma unroll
    for (int n = 0; n < 4; ++n) {
      short8v b = *reinterpret_cast<const short8v*>(&Wl[n * 16 + (lane & 15)][k0 * 32 + kh]);
      acc[n] = __builtin_amdgcn_mfma_f32_16x16x32_bf16(a, b, acc[n], 0, 0, 0);
    }
  }

  const int r0 = row0 + wv * 16;
#pragma unroll
  for (int j = 0; j < 4; ++j) {
    int rr = r0 + (lane >> 4) * 4 + j;
    if (rr < N_NODES) {
      float s = dinv[rr];
#pragma unroll
      for (int n = 0; n < 4; ++n)
        outA[(size_t)rr * 64 + n * 16 + (lane & 15)] = f2bf(acc[n][j] * s);
    }
  }
}

// ---------------- shared gather body: plain adds over pre-scaled h ----------------
#define GATHER_PLAIN(hbuf, EV, ENDV)                                               \
  uint4 sw = *reinterpret_cast<const uint4*>(&hbuf[(size_t)pv * 64 + f0]);         \
  float acc0 = bfu_lo(sw.x), acc1 = bfu_hi(sw.x);                                  \
  float acc2 = bfu_lo(sw.y), acc3 = bfu_hi(sw.y);                                  \
  float acc4 = bfu_lo(sw.z), acc5 = bfu_hi(sw.z);                                  \
  float acc6 = bfu_lo(sw.w), acc7 = bfu_hi(sw.w);                                  \
  int e = EV;                                                                      \
  const int end = ENDV;                                                            \
  while (e < end && (e & 3)) { EDGEP(hbuf, col[e]); ++e; }                         \
  for (; e + 8 <= end; e += 8) {                                                   \
    int4 ca = *reinterpret_cast<const int4*>(&col[e]);                             \
    int4 cb = *reinterpret_cast<const int4*>(&col[e + 4]);                         \
    EDGEP(hbuf, ca.x); EDGEP(hbuf, ca.y); EDGEP(hbuf, ca.z); EDGEP(hbuf, ca.w);    \
    EDGEP(hbuf, cb.x); EDGEP(hbuf, cb.y); EDGEP(hbuf, cb.z); EDGEP(hbuf, cb.w);    \
  }                                                                                \
  for (; e + 4 <= end; e += 4) {                                                   \
    int4 cc = *reinterpret_cast<const int4*>(&col[e]);                             \
    EDGEP(hbuf, cc.x); EDGEP(hbuf, cc.y); EDGEP(hbuf, cc.z); EDGEP(hbuf, cc.w);    \
  }                                                                                \
  for (; e < end; ++e) { EDGEP(hbuf, col[e]); }

#define EDGEP(hbuf, cc)                                                      \
  {                                                                          \
    uint4 w = *reinterpret_cast<const uint4*>(&hbuf[(size_t)(cc) * 64 + f0]); \
    acc0 += bfu_lo(w.x); acc1 += bfu_hi(w.x);                                \
    acc2 += bfu_lo(w.y); acc3 += bfu_hi(w.y);                                \
    acc4 += bfu_lo(w.z); acc5 += bfu_hi(w.z);                                \
    acc6 += bfu_lo(w.w); acc7 += bfu_hi(w.w);                                \
  }

// ---------------- agg1 (bucket-local perm, plain adds) + bias/relu + GEMM2 fused ----------------
__global__ __launch_bounds__(256) void k_agg_gemm(
    const unsigned short* __restrict__ h, const int* __restrict__ rowptr,
    const int* __restrict__ col, const float* __restrict__ dinv,
    const float* __restrict__ bias, const unsigned short* __restrict__ Wt2g,
    const int* __restrict__ perm, unsigned short* __restrict__ out) {
  const int t = threadIdx.x, lane = t & 63, wv = t >> 6;
  const int g = lane >> 3, f0 = (lane & 7) * 8;
  const int vbase = blockIdx.x * 32;
  const int lrow = wv * 8 + g;

  __shared__ unsigned short h1s[32][72];
  __shared__ int pvs[32];
  __shared__ float sdv[32];
  if (t < 32) {
    int p = perm[vbase + t];
    pvs[t] = p;
    sdv[t] = (p >= 0) ? dinv[p] : 0.0f;
  }
  __syncthreads();

  const int pv = pvs[lrow];
  if (pv >= 0) {
    const float sv = sdv[lrow];
    GATHER_PLAIN(h, rowptr[pv], rowptr[pv + 1])

    const float4 ba = *reinterpret_cast<const float4*>(&bias[f0]);
    const float4 bb = *reinterpret_cast<const float4*>(&bias[f0 + 4]);
    float v0 = fmaxf(fmaf(sv, acc0, ba.x), 0.0f);
    float v1 = fmaxf(fmaf(sv, acc1, ba.y), 0.0f);
    float v2 = fmaxf(fmaf(sv, acc2, ba.z), 0.0f);
    float v3 = fmaxf(fmaf(sv, acc3, ba.w), 0.0f);
    float v4 = fmaxf(fmaf(sv, acc4, bb.x), 0.0f);
    float v5 = fmaxf(fmaf(sv, acc5, bb.y), 0.0f);
    float v6 = fmaxf(fmaf(sv, acc6, bb.z), 0.0f);
    float v7 = fmaxf(fmaf(sv, acc7, bb.w), 0.0f);

    uint4 o;
    o.x = pack2(v0, v1); o.y = pack2(v2, v3);
    o.z = pack2(v4, v5); o.w = pack2(v6, v7);
    *reinterpret_cast<uint4*>(&h1s[lrow][f0]) = o;
  } else {
    uint4 z = {0, 0, 0, 0};
    *reinterpret_cast<uint4*>(&h1s[lrow][f0]) = z;
  }
  __syncthreads();

  // GEMM2: 32 tile rows x 64 cols; wave wv owns cols [wv*16, wv*16+16); K=64.
  const int kh = (lane >> 4) * 8;
  f32x4 acc2r[2] = {};
#pragma unroll
  for (int rt = 0; rt < 2; ++rt) {
#pragma unroll
    for (int k0 = 0; k0 < 64; k0 += 32) {
      short8v a = *reinterpret_cast<const short8v*>(&h1s[rt * 16 + (lane & 15)][k0 + kh]);
      short8v b = *reinterpret_cast<const short8v*>(
          Wt2g + (size_t)(wv * 16 + (lane & 15)) * 64 + k0 + kh);
      acc2r[rt] = __builtin_amdgcn_mfma_f32_16x16x32_bf16(a, b, acc2r[rt], 0, 0, 0);
    }
  }
#pragma unroll
  for (int rt = 0; rt < 2; ++rt) {
#pragma unroll
    for (int j = 0; j < 4; ++j) {
      int lr2 = rt * 16 + (lane >> 4) * 4 + j;
      int pvg = pvs[lr2];
      if (pvg >= 0)
        out[(size_t)pvg * 64 + wv * 16 + (lane & 15)] = f2bf(acc2r[rt][j] * sdv[lr2]);
    }
  }
}

// ---------------- agg2 (bucket-local perm, plain adds) + classifier fused ----------------
__global__ __launch_bounds__(256) void k_agg_fin(
    const unsigned short* __restrict__ h, const int* __restrict__ rowptr,
    const int* __restrict__ col, const float* __restrict__ dinv,
    const float* __restrict__ bias, const float* __restrict__ Wc,
    const float* __restrict__ bc, const int* __restrict__ perm,
    float* __restrict__ out) {
  const int t = threadIdx.x, lane = t & 63;
  const int g = lane >> 3, f0 = (lane & 7) * 8;
  const int vidx = blockIdx.x * 32 + (t >> 6) * 8 + g;
  const int pv = perm[vidx];
  if (pv < 0) return;

  GATHER_PLAIN(h, rowptr[pv], rowptr[pv + 1])

  const float sv = dinv[pv];
  const float4 ba = *reinterpret_cast<const float4*>(&bias[f0]);
  const float4 bb = *reinterpret_cast<const float4*>(&bias[f0 + 4]);
  const float4 wa = *reinterpret_cast<const float4*>(&Wc[f0]);
  const float4 wb = *reinterpret_cast<const float4*>(&Wc[f0 + 4]);
  float p = fmaxf(fmaf(sv, acc0, ba.x), 0.0f) * wa.x +
            fmaxf(fmaf(sv, acc1, ba.y), 0.0f) * wa.y +
            fmaxf(fmaf(sv, acc2, ba.z), 0.0f) * wa.z +
            fmaxf(fmaf(sv, acc3, ba.w), 0.0f) * wa.w +
            fmaxf(fmaf(sv, acc4, bb.x), 0.0f) * wb.x +
            fmaxf(fmaf(sv, acc5, bb.y), 0.0f) * wb.y +
            fmaxf(fmaf(sv, acc6, bb.z), 0.0f) * wb.z +
            fmaxf(fmaf(sv, acc7, bb.w), 0.0f) * wb.w;
  p += __shfl_xor(p, 1);
  p += __shfl_xor(p, 2);
  p += __shfl_xor(p, 4);
  if ((lane & 7) == 0) out[pv] = 1.0f / (1.0f + expf(-(p + bc[0])));
}

extern "C" void kernel_launch(void* const* d_in, const int* in_sizes, int n_in,
                              void* d_out, int out_size, void* d_ws, size_t ws_size,
                              hipStream_t stream) {
  const float* x  = (const float*)d_in[0];
  const int*   ei = (const int*)d_in[1];
  const float* W1 = (const float*)d_in[2];
  const float* b1 = (const float*)d_in[3];
  const float* W2 = (const float*)d_in[4];
  const float* b2 = (const float*)d_in[5];
  const float* Wc = (const float*)d_in[6];
  const float* bc = (const float*)d_in[7];
  float* out = (float*)d_out;

  const int* src = ei;
  const int* dst = ei + N_EDGES;

  // workspace layout (u32 units)
  unsigned* w = (unsigned*)d_ws;
  int*   bcur   = (int*)(w + 0);            // 256
  int*   rowptr = (int*)(w + 256);          // 50432 (needs 50001)
  int*   colidx = (int*)(w + 50688);        // 800000
  unsigned* ebuf = w + 850688;              // 196*8192 = 1605632
  float* dinv   = (float*)(w + 2456320);    // 50176
  int*   perm   = (int*)(w + 2506496);      // 50176
  unsigned short* Wt1g = (unsigned short*)(w + 2556672);  // 16384 ush
  unsigned short* Wt2g = (unsigned short*)(w + 2564864);  // 4096 ush
  unsigned short* A_bf = (unsigned short*)(w + 2566912);  // 3.2M ush
  unsigned short* B_bf = (unsigned short*)(w + 4166912);  // 3.2M ush

  k_prep<<<3, 256, 0, stream>>>(bcur, W1, W2, Wt1g, Wt2g);
  k_split<<<NCH, 256, 0, stream>>>(src, dst, bcur, ebuf);
  k_bucket<<<NBKT, 256, 0, stream>>>(ebuf, bcur, rowptr, colidx, dinv, perm);
  k_gemm1<<<NGB, 256, 0, stream>>>(x, Wt1g, dinv, A_bf);

  const int NAB = NBKT * 256 / 32;  // 1568 (perm is bucket-major, 50176 slots)
  k_agg_gemm<<<NAB, 256, 0, stream>>>(A_bf, rowptr, colidx, dinv, b1, Wt2g, perm, B_bf);
  k_agg_fin<<<NAB, 256, 0, stream>>>(B_bf, rowptr, colidx, dinv, b2, Wc, bc, perm, out);
}

// Round 12
// 100.662 us; speedup vs baseline: 1.1406x; 1.0592x over previous
//
#include <hip/hip_runtime.h>
#include <math.h>

#define N_NODES 50000
#define N_EDGES 800000
#define IN_DIM 256
#define HID 64
#define BKT 256
#define NBKT ((N_NODES + BKT - 1) / BKT)          // 196
#define CAP 8192                                  // ebuf slots per bucket (max real ~4400)
#define CHUNK 4096
#define NCH ((N_EDGES + CHUNK - 1) / CHUNK)       // 196
#define NGB ((N_NODES + 63) / 64)                 // 782

typedef short short8v __attribute__((ext_vector_type(8)));
typedef float f32x4 __attribute__((ext_vector_type(4)));
typedef unsigned uint4v __attribute__((ext_vector_type(4)));

__device__ __forceinline__ unsigned short f2bf(float f) {
  unsigned u = __builtin_bit_cast(unsigned, f);
  u += 0x7FFFu + ((u >> 16) & 1u);  // RNE
  return (unsigned short)(u >> 16);
}
__device__ __forceinline__ unsigned pack2(float a, float b) {
  return (unsigned)f2bf(a) | ((unsigned)f2bf(b) << 16);
}
__device__ __forceinline__ float bfu_lo(unsigned u) {
  return __builtin_bit_cast(float, u << 16);
}
__device__ __forceinline__ float bfu_hi(unsigned u) {
  return __builtin_bit_cast(float, u & 0xFFFF0000u);
}

// ---------------- prep: zero bcur + convert/transpose weights ----------------
__global__ void k_prep(int* __restrict__ bcur, const float* __restrict__ W1,
                       const float* __restrict__ W2, unsigned short* __restrict__ Wt1,
                       unsigned short* __restrict__ Wt2) {
  const int t = threadIdx.x;
  if (blockIdx.x == 0) {
    bcur[t] = 0;
  } else if (blockIdx.x == 1) {
    for (int j = 0; j < 64; ++j) {
      int lin = j * 256 + t;
      int k = lin >> 6, c = lin & 63;
      Wt1[c * 256 + k] = f2bf(W1[lin]);
    }
  } else {
    for (int j = 0; j < 16; ++j) {
      int lin = j * 256 + t;
      int k = lin >> 6, c = lin & 63;
      Wt2[c * 64 + k] = f2bf(W2[lin]);
    }
  }
}

// ---------------- fused: GEMM1 (blocks 0..NGB) || split (blocks NGB..) ----------------
// GEMM1: outA[r][c] = bf16( sum_k X[r][k]*W1[k][c] )  -- UNSCALED (bucket scales in place)
__global__ __launch_bounds__(256) void k_g1split(
    const float* __restrict__ X, const unsigned short* __restrict__ Wt1g,
    unsigned short* __restrict__ outA, const int* __restrict__ src,
    const int* __restrict__ dst, int* __restrict__ bcur, unsigned* __restrict__ ebuf) {
  __shared__ unsigned short Wl[64][IN_DIM + 8];  // gemm1 branch (33.8KB)
  __shared__ int cnt[NBKT];                      // split branch
  __shared__ int cur[NBKT];
  const int t = threadIdx.x;
  if (blockIdx.x < NGB) {
    const int lane = t & 63, wv = t >> 6;
    // stage Wt1 to LDS
#pragma unroll
    for (int j = 0; j < 8; ++j) {
      int grp = j * 256 + t;
      int r = grp >> 5, c = (grp & 31) * 8;
      *reinterpret_cast<short8v*>(&Wl[r][c]) =
          *reinterpret_cast<const short8v*>(&Wt1g[r * IN_DIM + c]);
    }
    const int row0 = blockIdx.x * 64;
    int r = row0 + wv * 16 + (lane & 15);
    if (r > N_NODES - 1) r = N_NODES - 1;  // clamp (stores guarded)
    const int kh = (lane >> 4) * 8;

    // issue ALL A loads up front (16 float4 in flight), pack to bf16 regs
    uint4v ap[8];
#pragma unroll
    for (int k0 = 0; k0 < 8; ++k0) {
      const float* Xp = X + (size_t)r * IN_DIM + k0 * 32 + kh;
      const float4 x0 = *reinterpret_cast<const float4*>(Xp);
      const float4 x1 = *reinterpret_cast<const float4*>(Xp + 4);
      uint4v p;
      p.x = pack2(x0.x, x0.y); p.y = pack2(x0.z, x0.w);
      p.z = pack2(x1.x, x1.y); p.w = pack2(x1.z, x1.w);
      ap[k0] = p;
    }
    __syncthreads();

    f32x4 acc[4] = {};
#pragma unroll
    for (int k0 = 0; k0 < 8; ++k0) {
      short8v a = __builtin_bit_cast(short8v, ap[k0]);
#pragma unroll
      for (int n = 0; n < 4; ++n) {
        short8v b = *reinterpret_cast<const short8v*>(&Wl[n * 16 + (lane & 15)][k0 * 32 + kh]);
        acc[n] = __builtin_amdgcn_mfma_f32_16x16x32_bf16(a, b, acc[n], 0, 0, 0);
      }
    }

    const int r0 = row0 + wv * 16;
#pragma unroll
    for (int j = 0; j < 4; ++j) {
      int rr = r0 + (lane >> 4) * 4 + j;
      if (rr < N_NODES) {
#pragma unroll
        for (int n = 0; n < 4; ++n)
          outA[(size_t)rr * 64 + n * 16 + (lane & 15)] = f2bf(acc[n][j]);
      }
    }
  } else {
    // ---- split: edges -> padded bucket regions (packed u32: src<<8 | dstLocal) ----
    for (int i = t; i < NBKT; i += 256) cnt[i] = 0;
    __syncthreads();
    const int base = (blockIdx.x - NGB) * CHUNK;
#pragma unroll
    for (int i = 0; i < CHUNK / 256; ++i) {
      int e = base + i * 256 + t;
      if (e < N_EDGES) atomicAdd(&cnt[dst[e] >> 8], 1);
    }
    __syncthreads();
    for (int i = t; i < NBKT; i += 256) {
      int c = cnt[i];
      cur[i] = c ? (i * CAP + atomicAdd(&bcur[i], c)) : 0;
    }
    __syncthreads();
#pragma unroll
    for (int i = 0; i < CHUNK / 256; ++i) {
      int e = base + i * 256 + t;
      if (e < N_EDGES) {
        int d = dst[e];
        int p = atomicAdd(&cur[d >> 8], 1);
        ebuf[p] = ((unsigned)src[e] << 8) | (unsigned)(d & 255);
      }
    }
  }
}

// ---------------- bucket: fine CSR + dinv + in-place h'-scaling ----------------
__global__ void k_bucket(const unsigned* __restrict__ ebuf, const int* __restrict__ bcur,
                         int* __restrict__ rowptr, int* __restrict__ colidx,
                         float* __restrict__ dinv, unsigned short* __restrict__ hbuf) {
  __shared__ int sA[256];
  __shared__ int sB[256];
  __shared__ float sD[256];
  const int b = blockIdx.x, t = threadIdx.x;

  // global colidx base via redundant scan of bucket counts
  sA[t] = (t < NBKT) ? bcur[t] : 0;
  __syncthreads();
  for (int d = 1; d < 256; d <<= 1) {
    int v = sA[t];
    int a = (t >= d) ? sA[t - d] : 0;
    __syncthreads();
    sA[t] = v + a;
    __syncthreads();
  }
  const int prefix = (b == 0) ? 0 : sA[b - 1];
  const int cntb = bcur[b];
  const int sbeg = b * CAP, send = sbeg + cntb;
  __syncthreads();

  // per-node degree within bucket
  sA[t] = 0;
  __syncthreads();
  for (int i = sbeg + t; i < send; i += 256) atomicAdd(&sA[ebuf[i] & 255], 1);
  __syncthreads();
  const int myc = sA[t];
  sB[t] = myc;
  __syncthreads();
  for (int d = 1; d < 256; d <<= 1) {
    int v = sB[t];
    int a = (t >= d) ? sB[t - d] : 0;
    __syncthreads();
    sB[t] = v + a;
    __syncthreads();
  }
  const int node = b * BKT + t;
  const bool valid = node < N_NODES;
  const int ex = prefix + sB[t] - myc;
  const float dv = rsqrtf((float)(myc + 1));
  sD[t] = dv;
  if (valid) {
    rowptr[node] = ex;
    dinv[node] = dv;
    if (node == N_NODES - 1) rowptr[N_NODES] = N_EDGES;
  }
  __syncthreads();
  sB[t] = ex;  // per-node cursor
  __syncthreads();
  for (int i = sbeg + t; i < send; i += 256) {
    unsigned p = ebuf[i];
    int pos = atomicAdd(&sB[p & 255], 1);
    colidx[pos] = (int)(p >> 8);
  }

  // in-place scale of this bucket's h rows: h'[v] = dinv[v]*h[v]
  // 8 lanes per row (16B each) -> 1KB contiguous per wave
  const int rsub = t >> 3, f8 = (t & 7) * 8;
#pragma unroll
  for (int g = 0; g < 8; ++g) {
    int lr = g * 32 + rsub;
    int nd = b * BKT + lr;
    if (nd < N_NODES) {
      float s = sD[lr];
      unsigned short* hp = &hbuf[(size_t)nd * 64 + f8];
      uint4 hv = *reinterpret_cast<const uint4*>(hp);
      uint4 o;
      o.x = pack2(s * bfu_lo(hv.x), s * bfu_hi(hv.x));
      o.y = pack2(s * bfu_lo(hv.y), s * bfu_hi(hv.y));
      o.z = pack2(s * bfu_lo(hv.z), s * bfu_hi(hv.z));
      o.w = pack2(s * bfu_lo(hv.w), s * bfu_hi(hv.w));
      *reinterpret_cast<uint4*>(hp) = o;
    }
  }
}

// ---------------- shared gather body: plain adds over pre-scaled h ----------------
#define EDGEP(hbuf, cc)                                                       \
  {                                                                           \
    uint4 w = *reinterpret_cast<const uint4*>(&hbuf[(size_t)(cc) * 64 + f0]); \
    acc0 += bfu_lo(w.x); acc1 += bfu_hi(w.x);                                 \
    acc2 += bfu_lo(w.y); acc3 += bfu_hi(w.y);                                 \
    acc4 += bfu_lo(w.z); acc5 += bfu_hi(w.z);                                 \
    acc6 += bfu_lo(w.w); acc7 += bfu_hi(w.w);                                 \
  }

#define GATHER_PLAIN(hbuf, EV, ENDV)                                               \
  uint4 sw = *reinterpret_cast<const uint4*>(&hbuf[(size_t)v * 64 + f0]);          \
  float acc0 = bfu_lo(sw.x), acc1 = bfu_hi(sw.x);                                  \
  float acc2 = bfu_lo(sw.y), acc3 = bfu_hi(sw.y);                                  \
  float acc4 = bfu_lo(sw.z), acc5 = bfu_hi(sw.z);                                  \
  float acc6 = bfu_lo(sw.w), acc7 = bfu_hi(sw.w);                                  \
  int e = EV;                                                                      \
  const int end = ENDV;                                                            \
  while (e < end && (e & 3)) { EDGEP(hbuf, col[e]); ++e; }                         \
  for (; e + 8 <= end; e += 8) {                                                   \
    int4 ca = *reinterpret_cast<const int4*>(&col[e]);                             \
    int4 cb = *reinterpret_cast<const int4*>(&col[e + 4]);                         \
    EDGEP(hbuf, ca.x); EDGEP(hbuf, ca.y); EDGEP(hbuf, ca.z); EDGEP(hbuf, ca.w);    \
    EDGEP(hbuf, cb.x); EDGEP(hbuf, cb.y); EDGEP(hbuf, cb.z); EDGEP(hbuf, cb.w);    \
  }                                                                                \
  for (; e + 4 <= end; e += 4) {                                                   \
    int4 cc = *reinterpret_cast<const int4*>(&col[e]);                             \
    EDGEP(hbuf, cc.x); EDGEP(hbuf, cc.y); EDGEP(hbuf, cc.z); EDGEP(hbuf, cc.w);    \
  }                                                                                \
  for (; e < end; ++e) { EDGEP(hbuf, col[e]); }

// ---------------- agg1 (plain adds) + bias/relu + GEMM2 fused ----------------
__global__ __launch_bounds__(256) void k_agg_gemm(
    const unsigned short* __restrict__ h, const int* __restrict__ rowptr,
    const int* __restrict__ col, const float* __restrict__ dinv,
    const float* __restrict__ bias, const unsigned short* __restrict__ Wt2g,
    unsigned short* __restrict__ out) {
  const int t = threadIdx.x, lane = t & 63, wv = t >> 6;
  const int g = lane >> 3, f0 = (lane & 7) * 8;
  const int vbase = blockIdx.x * 32;
  const int v = vbase + wv * 8 + g;
  const int lrow = wv * 8 + g;

  __shared__ unsigned short h1s[32][72];  // pad: 144B stride

  if (v < N_NODES) {
    const float sv = dinv[v];
    GATHER_PLAIN(h, rowptr[v], rowptr[v + 1])

    const float4 ba = *reinterpret_cast<const float4*>(&bias[f0]);
    const float4 bb = *reinterpret_cast<const float4*>(&bias[f0 + 4]);
    float v0 = fmaxf(fmaf(sv, acc0, ba.x), 0.0f);
    float v1 = fmaxf(fmaf(sv, acc1, ba.y), 0.0f);
    float v2 = fmaxf(fmaf(sv, acc2, ba.z), 0.0f);
    float v3 = fmaxf(fmaf(sv, acc3, ba.w), 0.0f);
    float v4 = fmaxf(fmaf(sv, acc4, bb.x), 0.0f);
    float v5 = fmaxf(fmaf(sv, acc5, bb.y), 0.0f);
    float v6 = fmaxf(fmaf(sv, acc6, bb.z), 0.0f);
    float v7 = fmaxf(fmaf(sv, acc7, bb.w), 0.0f);

    uint4 o;
    o.x = pack2(v0, v1); o.y = pack2(v2, v3);
    o.z = pack2(v4, v5); o.w = pack2(v6, v7);
    *reinterpret_cast<uint4*>(&h1s[lrow][f0]) = o;
  } else {
    uint4 z = {0, 0, 0, 0};
    *reinterpret_cast<uint4*>(&h1s[lrow][f0]) = z;
  }
  __syncthreads();

  // GEMM2: 32 nodes x 64 cols; wave wv owns cols [wv*16, wv*16+16); K=64.
  const int kh = (lane >> 4) * 8;
  f32x4 acc2r[2] = {};
#pragma unroll
  for (int rt = 0; rt < 2; ++rt) {
#pragma unroll
    for (int k0 = 0; k0 < 64; k0 += 32) {
      short8v a = *reinterpret_cast<const short8v*>(&h1s[rt * 16 + (lane & 15)][k0 + kh]);
      short8v b = *reinterpret_cast<const short8v*>(
          Wt2g + (size_t)(wv * 16 + (lane & 15)) * 64 + k0 + kh);
      acc2r[rt] = __builtin_amdgcn_mfma_f32_16x16x32_bf16(a, b, acc2r[rt], 0, 0, 0);
    }
  }
#pragma unroll
  for (int rt = 0; rt < 2; ++rt) {
#pragma unroll
    for (int j = 0; j < 4; ++j) {
      int vg = vbase + rt * 16 + (lane >> 4) * 4 + j;
      if (vg < N_NODES)
        out[(size_t)vg * 64 + wv * 16 + (lane & 15)] = f2bf(acc2r[rt][j] * dinv[vg]);
    }
  }
}

// ---------------- agg2 (plain adds) + classifier fused ----------------
__global__ __launch_bounds__(256) void k_agg_fin(
    const unsigned short* __restrict__ h, const int* __restrict__ rowptr,
    const int* __restrict__ col, const float* __restrict__ dinv,
    const float* __restrict__ bias, const float* __restrict__ Wc,
    const float* __restrict__ bc, float* __restrict__ out) {
  const int t = threadIdx.x, lane = t & 63;
  const int g = lane >> 3, f0 = (lane & 7) * 8;
  const int v = blockIdx.x * 32 + (t >> 6) * 8 + g;
  if (v >= N_NODES) return;

  GATHER_PLAIN(h, rowptr[v], rowptr[v + 1])

  const float sv = dinv[v];
  const float4 ba = *reinterpret_cast<const float4*>(&bias[f0]);
  const float4 bb = *reinterpret_cast<const float4*>(&bias[f0 + 4]);
  const float4 wa = *reinterpret_cast<const float4*>(&Wc[f0]);
  const float4 wb = *reinterpret_cast<const float4*>(&Wc[f0 + 4]);
  float p = fmaxf(fmaf(sv, acc0, ba.x), 0.0f) * wa.x +
            fmaxf(fmaf(sv, acc1, ba.y), 0.0f) * wa.y +
            fmaxf(fmaf(sv, acc2, ba.z), 0.0f) * wa.z +
            fmaxf(fmaf(sv, acc3, ba.w), 0.0f) * wa.w +
            fmaxf(fmaf(sv, acc4, bb.x), 0.0f) * wb.x +
            fmaxf(fmaf(sv, acc5, bb.y), 0.0f) * wb.y +
            fmaxf(fmaf(sv, acc6, bb.z), 0.0f) * wb.z +
            fmaxf(fmaf(sv, acc7, bb.w), 0.0f) * wb.w;
  p += __shfl_xor(p, 1);
  p += __shfl_xor(p, 2);
  p += __shfl_xor(p, 4);
  if ((lane & 7) == 0) out[v] = 1.0f / (1.0f + expf(-(p + bc[0])));
}

extern "C" void kernel_launch(void* const* d_in, const int* in_sizes, int n_in,
                              void* d_out, int out_size, void* d_ws, size_t ws_size,
                              hipStream_t stream) {
  const float* x  = (const float*)d_in[0];
  const int*   ei = (const int*)d_in[1];
  const float* W1 = (const float*)d_in[2];
  const float* b1 = (const float*)d_in[3];
  const float* W2 = (const float*)d_in[4];
  const float* b2 = (const float*)d_in[5];
  const float* Wc = (const float*)d_in[6];
  const float* bc = (const float*)d_in[7];
  float* out = (float*)d_out;

  const int* src = ei;
  const int* dst = ei + N_EDGES;

  // workspace layout (u32 units)
  unsigned* w = (unsigned*)d_ws;
  int*   bcur   = (int*)(w + 0);            // 256
  int*   rowptr = (int*)(w + 256);          // 50432 (needs 50001)
  int*   colidx = (int*)(w + 50688);        // 800000
  unsigned* ebuf = w + 850688;              // 196*8192 = 1605632
  float* dinv   = (float*)(w + 2456320);    // 50176
  unsigned short* Wt1g = (unsigned short*)(w + 2506496);  // 16384 ush
  unsigned short* Wt2g = (unsigned short*)(w + 2514688);  // 4096 ush
  unsigned short* A_bf = (unsigned short*)(w + 2516736);  // 3.2M ush
  unsigned short* B_bf = (unsigned short*)(w + 4116736);  // 3.2M ush

  k_prep<<<3, 256, 0, stream>>>(bcur, W1, W2, Wt1g, Wt2g);
  // GEMM1 (unscaled) runs concurrently with edge split in one dispatch
  k_g1split<<<NGB + NCH, 256, 0, stream>>>(x, Wt1g, A_bf, src, dst, bcur, ebuf);
  // CSR build + dinv + in-place scaling of h' rows
  k_bucket<<<NBKT, 256, 0, stream>>>(ebuf, bcur, rowptr, colidx, dinv, A_bf);

  const int NAB = (N_NODES + 31) / 32;  // 1563
  k_agg_gemm<<<NAB, 256, 0, stream>>>(A_bf, rowptr, colidx, dinv, b1, Wt2g, B_bf);
  k_agg_fin<<<NAB, 256, 0, stream>>>(B_bf, rowptr, colidx, dinv, b2, Wc, bc, out);
}